// Round 11
// baseline (502.567 us; speedup 1.0000x reference)
//
#include <hip/hip_runtime.h>
#include <math.h>

// Problem constants (match reference)
constexpr int B    = 4;
constexpr int N    = 32768;   // 2^15
constexpr int K    = 16;
constexpr int CIN  = 32;
constexpr int H    = 32;
constexpr int COUT = 32;
constexpr int NODES = B * N;            // 131072
constexpr int E      = B * N * K;       // 2097152 edges

// Bucketing: one bucket per 64 dst nodes == one gather block
constexpr int BPB        = 512;          // buckets per batch (N/64)
constexpr int NBUCKETS   = B * BPB;      // 2048
constexpr int BUCKET_CAP = 2048;         // mean 1024 -> huge headroom
constexpr int BIN_EDGES  = 8192;         // edges per bin block
constexpr int BIN_BLOCKS = E / BIN_EDGES;       // 256 (64 per batch)
constexpr int BIN_THREADS = 1024;        // 16 waves/CU for latency hiding
constexpr int EPT = BIN_EDGES / BIN_THREADS;    // 8 edges per thread

// ---------------------------------------------------------------------------
// Kernel 1: fc1 + fold grid_weight and gaussian normalizer into hh[node][h]
// ---------------------------------------------------------------------------
__global__ __launch_bounds__(256) void k_fc1(const float* __restrict__ x,
                                             const float* __restrict__ grid_weight,
                                             const float* __restrict__ W1,
                                             const float* __restrict__ b1,
                                             const float* __restrict__ baseweight,
                                             float* __restrict__ hh)
{
    __shared__ float sW1[H * CIN];
    __shared__ float sb1[H];
    __shared__ float scoef[H];
    const int tid = threadIdx.x;
    for (int i = tid; i < H * CIN; i += 256) sW1[i] = W1[i];
    if (tid < H) {
        sb1[tid] = b1[tid];
        float t = baseweight[tid] * (float)(1.0 / M_PI);
        scoef[tid] = t * sqrtf(t);           // (bw/pi)^1.5
    }
    __syncthreads();

    const int node = blockIdx.x * 256 + tid;
    const int b = node >> 15;
    const int n = node & (N - 1);
    const float* xb = x + (size_t)b * CIN * N + n;

    float acc[H];
#pragma unroll
    for (int h = 0; h < H; ++h) acc[h] = sb1[h];
#pragma unroll
    for (int c = 0; c < CIN; ++c) {
        float xv = xb[(size_t)c * N];
#pragma unroll
        for (int h = 0; h < H; ++h) acc[h] = fmaf(xv, sW1[h * CIN + c], acc[h]);
    }
    const float gw = grid_weight[node];

    float4* dst = (float4*)(hh + (size_t)node * H);
#pragma unroll
    for (int i = 0; i < H / 4; ++i) {
        float4 v;
        v.x = acc[4 * i + 0] * gw * scoef[4 * i + 0];
        v.y = acc[4 * i + 1] * gw * scoef[4 * i + 1];
        v.z = acc[4 * i + 2] * gw * scoef[4 * i + 2];
        v.w = acc[4 * i + 3] * gw * scoef[4 * i + 3];
        dst[i] = v;
    }
}

// ---------------------------------------------------------------------------
// k_bin v3: 1024 threads; edst register-cached between passes (saves 8 MB
// re-read). LDS counting-sort of 8192 edges into 512 buckets, flat parallel
// flush. Payload: (d_local << 16) | src_local.
// ---------------------------------------------------------------------------
__global__ __launch_bounds__(BIN_THREADS) void k_bin(const int* __restrict__ esrc,
                                                     const int* __restrict__ edst,
                                                     int* __restrict__ gcur,
                                                     unsigned* __restrict__ gbucket)
{
    __shared__ int hist[BPB];
    __shared__ int lbase[BPB];
    __shared__ int cur[BPB];
    __shared__ int gbase[BPB];
    __shared__ int sc[256];
    __shared__ unsigned staged[BIN_EDGES];   // 32 KB

    const int tid = threadIdx.x;
    const int e0  = blockIdx.x * BIN_EDGES;
    const int batch = blockIdx.x >> 6;       // 64 blocks per batch

    for (int i = tid; i < BPB; i += BIN_THREADS) hist[i] = 0;
    __syncthreads();

    // pass 1: histogram over dst>>6 (8 edges/thread, dst kept in registers)
    int ed_r[EPT];
#pragma unroll
    for (int i = 0; i < EPT; ++i) {
        ed_r[i] = edst[e0 + i * BIN_THREADS + tid];
        atomicAdd(&hist[ed_r[i] >> 6], 1);
    }
    __syncthreads();

    // exclusive scan of 512 (pairwise + 256-wide Hillis-Steele)
    int h0 = 0, h1 = 0;
    if (tid < 256) {
        h0 = hist[2 * tid];
        h1 = hist[2 * tid + 1];
        sc[tid] = h0 + h1;
    }
    __syncthreads();
    for (int off = 1; off < 256; off <<= 1) {
        int v = 0;
        if (tid < 256 && tid >= off) v = sc[tid - off];
        __syncthreads();
        if (tid < 256) sc[tid] += v;
        __syncthreads();
    }
    if (tid < 256) {
        const int pairExcl = sc[tid] - (h0 + h1);
        lbase[2 * tid]     = pairExcl;
        lbase[2 * tid + 1] = pairExcl + h0;
        cur[2 * tid]       = pairExcl;
        cur[2 * tid + 1]   = pairExcl + h0;
    }
    __syncthreads();

    // acquire all per-bucket global bases in parallel
    if (tid < BPB) gbase[tid] = atomicAdd(&gcur[batch * BPB + tid], hist[tid]);

    // pass 2: place payloads into LDS staging (counting-sort scatter)
#pragma unroll
    for (int i = 0; i < EPT; ++i) {
        const int s = esrc[e0 + i * BIN_THREADS + tid];
        const int d = ed_r[i];
        const int pos = atomicAdd(&cur[d >> 6], 1);
        staged[pos] = ((unsigned)d << 16) | (unsigned)s;
    }
    __syncthreads();

    // flat parallel flush: all 1024 threads, coalesced-run writes
    unsigned* gb_batch = gbucket + (size_t)batch * BPB * BUCKET_CAP;
#pragma unroll
    for (int i = 0; i < EPT; ++i) {
        const int idx = i * BIN_THREADS + tid;
        const unsigned v = staged[idx];
        const int bkt = (int)(v >> 22);
        const int p = gbase[bkt] + (idx - lbase[bkt]);
        if (p < BUCKET_CAP) gb_batch[(size_t)bkt * BUCKET_CAP + p] = v;
    }
}

// ---------------------------------------------------------------------------
// k_gather3: one block per bucket (64 dst nodes), XCD-batch-swizzled.
// No intra-bucket sort: edges streamed flat in 32-edge chunks per 32-lane
// group; phase1 fully lane-parallel (payload + src grid + d2); phase2
// broadcasts from registers and accumulates via LDS float atomicAdd into
// acc[64][33] (padded: 2 accesses/bank per wave = conflict-free).
// Then fc2 from acc + transposed coalesced store.
// ---------------------------------------------------------------------------
__global__ __launch_bounds__(256) void k_gather3(const float* __restrict__ grid,
                                                 const float* __restrict__ baseweight,
                                                 const float* __restrict__ hh,
                                                 const unsigned* __restrict__ gbucket,
                                                 const int* __restrict__ gcur,
                                                 const float* __restrict__ W2,
                                                 const float* __restrict__ b2,
                                                 float* __restrict__ out)
{
    __shared__ float sW2[COUT][H + 1];
    __shared__ float sb2[COUT];
    __shared__ float sbw[H];
    __shared__ float sgrid[64 * 3];          // dst grid, staged
    __shared__ float acc[64][H + 1];         // per-dst channel accumulators
    __shared__ float stage[64][COUT + 1];

    const int tid = threadIdx.x;
    for (int i = tid; i < COUT * H; i += 256) sW2[i >> 5][i & 31] = W2[i];
    if (tid < COUT) sb2[tid] = b2[tid];
    if (tid < H)    sbw[tid] = baseweight[tid];
    for (int i = tid; i < 64 * (H + 1); i += 256) ((float*)acc)[i] = 0.0f;

    // XCD-batch swizzle (bijective): batch from bits[2:1], bloc from the rest
    const int bi    = blockIdx.x;
    const int batch = (bi & 7) >> 1;
    const int bloc  = ((bi >> 3) << 1) | (bi & 1);
    const int gb    = batch * BPB + bloc;
    const int bb    = batch * N;             // batch node base
    const int n0    = bloc * 64;             // first dst (batch-local)

    if (tid < 192) sgrid[tid] = grid[((size_t)(bb + n0)) * 3 + tid];  // coalesced
    __syncthreads();

    const int cnt = min(gcur[gb], BUCKET_CAP);
    const unsigned* bp = gbucket + (size_t)gb * BUCKET_CAP;

    const int g    = tid >> 5;               // 32-lane group 0..7
    const int lane = tid & 31;               // channel
    const float bwl = sbw[lane];

    // flat edge stream: group g takes chunks g, g+8, g+16, ...
    for (int c = g; c * 32 < cnt; c += 8) {
        const int m = min(32, cnt - c * 32);

        // phase 1: fully parallel per-lane edge fetch + d2
        unsigned v_l = 0;
        float d2_l = 0.0f;
        if (lane < m) {
            v_l = bp[c * 32 + lane];                    // coalesced 128 B
            const int s  = bb + (int)(v_l & 0xFFFFu);
            const int dl = (int)((v_l >> 16) & 63u);
            const float dx = grid[s * 3 + 0] - sgrid[dl * 3 + 0];
            const float dy = grid[s * 3 + 1] - sgrid[dl * 3 + 1];
            const float dz = grid[s * 3 + 2] - sgrid[dl * 3 + 2];
            d2_l = dx * dx + dy * dy + dz * dz;
        }

        // phase 2: broadcast, 4-deep independent hh loads, LDS atomic acc
        int i = 0;
        for (; i + 4 <= m; i += 4) {
            const unsigned v0 = __shfl(v_l, i + 0, 32);
            const unsigned v1 = __shfl(v_l, i + 1, 32);
            const unsigned v2 = __shfl(v_l, i + 2, 32);
            const unsigned v3 = __shfl(v_l, i + 3, 32);
            const float w0 = __shfl(d2_l, i + 0, 32);
            const float w1 = __shfl(d2_l, i + 1, 32);
            const float w2 = __shfl(d2_l, i + 2, 32);
            const float w3 = __shfl(d2_l, i + 3, 32);
            const float f0 = hh[(size_t)(bb + (v0 & 0xFFFFu)) * H + lane];
            const float f1 = hh[(size_t)(bb + (v1 & 0xFFFFu)) * H + lane];
            const float f2 = hh[(size_t)(bb + (v2 & 0xFFFFu)) * H + lane];
            const float f3 = hh[(size_t)(bb + (v3 & 0xFFFFu)) * H + lane];
            atomicAdd(&acc[(v0 >> 16) & 63][lane], __expf(-bwl * w0) * f0);
            atomicAdd(&acc[(v1 >> 16) & 63][lane], __expf(-bwl * w1) * f1);
            atomicAdd(&acc[(v2 >> 16) & 63][lane], __expf(-bwl * w2) * f2);
            atomicAdd(&acc[(v3 >> 16) & 63][lane], __expf(-bwl * w3) * f3);
        }
        for (; i < m; ++i) {
            const unsigned v = __shfl(v_l, i, 32);
            const float    w = __shfl(d2_l, i, 32);
            const float    f = hh[(size_t)(bb + (v & 0xFFFFu)) * H + lane];
            atomicAdd(&acc[(v >> 16) & 63][lane], __expf(-bwl * w) * f);
        }
    }
    __syncthreads();

    // fc2: node nl handled by group g in 8 rounds; acc reads are broadcasts
#pragma unroll
    for (int r = 0; r < 8; ++r) {
        const int nl = g * 8 + r;
        float o_val = sb2[lane];
#pragma unroll
        for (int h = 0; h < H; ++h)
            o_val = fmaf(acc[nl][h], sW2[lane][h], o_val);
        stage[nl][lane] = o_val;
    }
    __syncthreads();

    // coalesced transposed write: out[batch, o, n0..n0+63]
    float* ob = out + (size_t)batch * COUT * N + n0;
#pragma unroll
    for (int i = 0; i < 8; ++i) {
        const int flat = i * 256 + tid;
        const int o = flat >> 6;
        const int j = flat & 63;
        ob[(size_t)o * N + j] = stage[j][o];
    }
}

// ---------------------------------------------------------------------------
extern "C" void kernel_launch(void* const* d_in, const int* in_sizes, int n_in,
                              void* d_out, int out_size, void* d_ws, size_t ws_size,
                              hipStream_t stream)
{
    const float* x    = (const float*)d_in[0];
    const float* grid = (const float*)d_in[1];
    const float* gw   = (const float*)d_in[2];
    const int*   es   = (const int*)d_in[3];
    const int*   ed   = (const int*)d_in[4];
    const float* W1   = (const float*)d_in[5];
    const float* b1   = (const float*)d_in[6];
    const float* W2   = (const float*)d_in[7];
    const float* b2   = (const float*)d_in[8];
    const float* bw   = (const float*)d_in[9];
    float* out = (float*)d_out;

    // workspace: hh 16 MB | gbucket 16 MB | gcur 8 KB   (33.57 MB total)
    char* w = (char*)d_ws;
    float*    hh      = (float*)(w);
    unsigned* gbucket = (unsigned*)(w + (size_t)NODES * H * 4);
    int*      gcur    = (int*)(w + (size_t)NODES * H * 4
                                 + (size_t)NBUCKETS * BUCKET_CAP * 4);

    hipMemsetAsync(gcur, 0, (size_t)NBUCKETS * sizeof(int), stream);

    k_fc1<<<NODES / 256, 256, 0, stream>>>(x, gw, W1, b1, bw, hh);
    k_bin<<<BIN_BLOCKS, BIN_THREADS, 0, stream>>>(es, ed, gcur, gbucket);
    k_gather3<<<NBUCKETS, 256, 0, stream>>>(grid, bw, hh, gbucket, gcur,
                                            W2, b2, out);
}